// Round 11
// baseline (6518.908 us; speedup 1.0000x reference)
//
#include <hip/hip_runtime.h>
#include <math.h>

constexpr int BB = 32;     // batch
constexpr int NN_ = 512;   // sequence length
constexpr int DIN = 256;
constexpr int DH = 128;
constexpr int NITER = 10;
constexpr long HSTR = (long)NN_ * DH;    // 65536
constexpr long SSTR = (long)NN_ * NN_;   // 262144
constexpr long LSTR = 512L * 512L;       // 262144

__device__ __forceinline__ unsigned f2mono(float f) {
    unsigned u = __float_as_uint(f);
    return (u & 0x80000000u) ? ~u : (u | 0x80000000u);
}
__device__ __forceinline__ float mono2f(unsigned u) {
    return __uint_as_float((u & 0x80000000u) ? (u & 0x7fffffffu) : ~u);
}

// ---------------------------------------------------------------------------
// 128x128 in-register block-GJ inversion (16 rank-8 stages), verified.
// r[8][8] per thread (tx,ty), 256 active threads (pass LOCAL tid 0..255).
// Callable from multi-group blocks: all groups must call with aligned
// barriers (identical loop structure). Opens with __syncthreads().
// ---------------------------------------------------------------------------
__device__ __forceinline__ float invert128(float r[8][8], int tid,
        float (*RowP)[8][132], float (*ColPT)[8][132], float (*Rnew)[8][132])
{
    int tx = tid & 15, ty = tid >> 4;
    int lane = tid & 63, w = tid >> 6;
    int li = lane >> 3, lj = lane & 7;
    const bool act = (tid < 256);
    float lacc = 0.f;
    __syncthreads();
    for (int s8 = 0; s8 < 16; ++s8) {
        int p = s8 & 1;
        if (act && ty == s8) {
            #pragma unroll
            for (int i = 0; i < 8; ++i)
                #pragma unroll
                for (int j = 0; j < 8; ++j)
                    RowP[p][i][tx * 8 + j] = r[i][j];
        }
        if (act && tx == s8) {
            float sub = (ty == s8) ? 1.f : 0.f;
            #pragma unroll
            for (int i = 0; i < 8; ++i)
                #pragma unroll
                for (int j = 0; j < 8; ++j)
                    ColPT[p][j][ty * 8 + i] = r[i][j] - ((i == j) ? sub : 0.f);
        }
        __syncthreads();
        // all waves: invert 8x8 pivot block via shuffles
        float d = RowP[p][li][s8 * 8 + lj];
        float prod = 1.f;
        #pragma unroll
        for (int s = 0; s < 8; ++s) {
            float pv = __shfl(d, s * 9);
            prod *= pv;
            float pinv = 1.0f / pv;
            float rv = __shfl(d, s * 8 + lj);
            float cv = __shfl(d, li * 8 + s);
            float nd;
            if (li == s && lj == s)  nd = pinv;
            else if (li == s)        nd = rv * pinv;
            else if (lj == s)        nd = -cv * pinv;
            else                     nd = d - cv * pinv * rv;
            d = nd;
        }
        lacc += logf(fabsf(prod));
        // Rnew = Dinv @ RowP; pivot-col slice overwritten with I + Dinv
        if (act) {
            int sr = li;
            int jq = w * 32 + lj * 4;
            float dsr[8];
            #pragma unroll
            for (int t = 0; t < 8; ++t) dsr[t] = __shfl(d, (lane & 56) + t);
            float a0 = 0.f, a1 = 0.f, a2 = 0.f, a3 = 0.f;
            #pragma unroll
            for (int t = 0; t < 8; ++t) {
                float4 rp = *(const float4*)&RowP[p][t][jq];
                a0 += dsr[t] * rp.x; a1 += dsr[t] * rp.y;
                a2 += dsr[t] * rp.z; a3 += dsr[t] * rp.w;
            }
            if ((jq >> 3) == s8) {
                if ((jq & 7) == 0) {
                    a0 = dsr[0] + ((sr == 0) ? 1.f : 0.f);
                    a1 = dsr[1] + ((sr == 1) ? 1.f : 0.f);
                    a2 = dsr[2] + ((sr == 2) ? 1.f : 0.f);
                    a3 = dsr[3] + ((sr == 3) ? 1.f : 0.f);
                } else {
                    a0 = dsr[4] + ((sr == 4) ? 1.f : 0.f);
                    a1 = dsr[5] + ((sr == 5) ? 1.f : 0.f);
                    a2 = dsr[6] + ((sr == 6) ? 1.f : 0.f);
                    a3 = dsr[7] + ((sr == 7) ? 1.f : 0.f);
                }
            }
            *(float4*)&Rnew[p][sr][jq] = make_float4(a0, a1, a2, a3);
        }
        __syncthreads();
        // uniform branch-free update: r -= ColPT^T @ Rnew
        if (act) {
            #pragma unroll
            for (int t = 0; t < 8; ++t) {
                float cp[8], rn[8];
                *(float4*)&cp[0] = *(const float4*)&ColPT[p][t][ty * 8];
                *(float4*)&cp[4] = *(const float4*)&ColPT[p][t][ty * 8 + 4];
                *(float4*)&rn[0] = *(const float4*)&Rnew[p][t][tx * 8];
                *(float4*)&rn[4] = *(const float4*)&Rnew[p][t][tx * 8 + 4];
                #pragma unroll
                for (int i = 0; i < 8; ++i)
                    #pragma unroll
                    for (int j = 0; j < 8; ++j)
                        r[i][j] -= cp[i] * rn[j];
            }
        }
        // no trailing barrier: panels double-buffered
    }
    return lacc;
}

// ---------------------------------------------------------------------------
// Generic fp32 tiled GEMM (64x64 tile, BK=16, 4x4/thread), prefetched.
// ---------------------------------------------------------------------------
template<int AMODE, int BMODE, int EPI>
__global__ __launch_bounds__(256) void gemm64(
    const float* __restrict__ A, const float* __restrict__ Bm,
    float* __restrict__ C, const float* __restrict__ Dp, float* __restrict__ C2,
    int Mdim, int Ndim, int Kdim,
    long sA, long sB, long sC, long sD)
{
    constexpr int BK = 16;
    __shared__ float As[BK][64 + 4];
    __shared__ float Bs[BK][64 + 4];
    int b = blockIdx.z;
    const float* Ab = A + (long)b * sA;
    const float* Bb = Bm + (long)b * sB;
    int m0 = blockIdx.x * 64, n0 = blockIdx.y * 64;
    int tid = threadIdx.x;
    int tx = tid & 15, ty = tid >> 4;
    float acc[4][4] = {};

    int arow, acol, brow, bcol;
    if (AMODE == 0) { arow = tid >> 2; acol = (tid & 3) * 4; }
    else            { arow = tid >> 4; acol = (tid & 15) * 4; }
    if (BMODE == 0) { brow = tid >> 4; bcol = (tid & 15) * 4; }
    else            { brow = tid >> 2; bcol = (tid & 3) * 4; }

    float4 av, bv;
    if (AMODE == 0) av = *(const float4*)(Ab + (long)(m0 + arow) * Kdim + acol);
    else            av = *(const float4*)(Ab + (long)(0 + arow) * Mdim + m0 + acol);
    if (BMODE == 0) bv = *(const float4*)(Bb + (long)(0 + brow) * Ndim + n0 + bcol);
    else            bv = *(const float4*)(Bb + (long)(n0 + brow) * Kdim + bcol);

    for (int k0 = 0; k0 < Kdim; k0 += BK) {
        __syncthreads();
        if (AMODE == 0) {
            As[acol + 0][arow] = av.x; As[acol + 1][arow] = av.y;
            As[acol + 2][arow] = av.z; As[acol + 3][arow] = av.w;
        } else {
            *(float4*)&As[arow][acol] = av;
        }
        if (BMODE == 0) {
            *(float4*)&Bs[brow][bcol] = bv;
        } else {
            Bs[bcol + 0][brow] = bv.x; Bs[bcol + 1][brow] = bv.y;
            Bs[bcol + 2][brow] = bv.z; Bs[bcol + 3][brow] = bv.w;
        }
        float4 av2, bv2;
        if (k0 + BK < Kdim) {
            int k1 = k0 + BK;
            if (AMODE == 0) av2 = *(const float4*)(Ab + (long)(m0 + arow) * Kdim + k1 + acol);
            else            av2 = *(const float4*)(Ab + (long)(k1 + arow) * Mdim + m0 + acol);
            if (BMODE == 0) bv2 = *(const float4*)(Bb + (long)(k1 + brow) * Ndim + n0 + bcol);
            else            bv2 = *(const float4*)(Bb + (long)(n0 + brow) * Kdim + k1 + bcol);
        }
        __syncthreads();
        #pragma unroll
        for (int k = 0; k < BK; ++k) {
            float4 a4 = *(const float4*)&As[k][ty * 4];
            float4 b4 = *(const float4*)&Bs[k][tx * 4];
            float avv[4] = {a4.x, a4.y, a4.z, a4.w};
            float bvv[4] = {b4.x, b4.y, b4.z, b4.w};
            #pragma unroll
            for (int i = 0; i < 4; ++i)
                #pragma unroll
                for (int j = 0; j < 4; ++j)
                    acc[i][j] += avv[i] * bvv[j];
        }
        av = av2; bv = bv2;
    }

    int r0 = m0 + ty * 4, c0 = n0 + tx * 4;
    if (EPI == 0) {
        float* Cb = C + (long)b * sC;
        #pragma unroll
        for (int i = 0; i < 4; ++i)
            *(float4*)(Cb + (long)(r0 + i) * Ndim + c0) =
                make_float4(acc[i][0], acc[i][1], acc[i][2], acc[i][3]);
    } else if (EPI == 1) {
        float4 bias = *(const float4*)(Dp + c0);
        float bb4[4] = {bias.x, bias.y, bias.z, bias.w};
        #pragma unroll
        for (int i = 0; i < 4; ++i) {
            float pre[4];
            #pragma unroll
            for (int j = 0; j < 4; ++j) pre[j] = acc[i][j] + bb4[j];
            *(float4*)(C2 + (long)(r0 + i) * Ndim + c0) =
                make_float4(pre[0], pre[1], pre[2], pre[3]);
            *(float4*)(C + (long)(r0 + i) * Ndim + c0) =
                make_float4(fmaxf(pre[0], 0.f), fmaxf(pre[1], 0.f),
                            fmaxf(pre[2], 0.f), fmaxf(pre[3], 0.f));
        }
    } else {
        const float* Db = Dp + (long)b * sD;
        float* Cb = C + (long)b * sC;
        #pragma unroll
        for (int i = 0; i < 4; ++i) {
            float4 d = *(const float4*)(Db + (long)(r0 + i) * Ndim + c0);
            float pre[4] = {acc[i][0] + d.x, acc[i][1] + d.y,
                            acc[i][2] + d.z, acc[i][3] + d.w};
            *(float4*)(Cb + (long)(r0 + i) * Ndim + c0) =
                make_float4(fmaxf(pre[0], 0.f), fmaxf(pre[1], 0.f),
                            fmaxf(pre[2], 0.f), fmaxf(pre[3], 0.f));
        }
    }
}

// ---------------------------------------------------------------------------
// 32x64-tile fp32 GEMM for the K=512 feedback matmuls (C = relu(acc + D)).
// ---------------------------------------------------------------------------
template<int AMODE>
__global__ __launch_bounds__(256) void gemm32(
    const float* __restrict__ A, const float* __restrict__ Bm,
    float* __restrict__ C, const float* __restrict__ Dp,
    int Mdim, int Ndim, int Kdim,
    long sA, long sB, long sC, long sD)
{
    constexpr int BK = 16;
    __shared__ float As[BK][36];
    __shared__ float Bs[BK][68];
    int b = blockIdx.z;
    const float* Ab = A + (long)b * sA;
    const float* Bb = Bm + (long)b * sB;
    int m0 = blockIdx.x * 32, n0 = blockIdx.y * 64;
    int tid = threadIdx.x;
    int tx = tid & 15, ty = tid >> 4;
    float acc[2][4] = {};

    int arow, acol;
    if (AMODE == 0) { arow = tid >> 2; acol = (tid & 3) * 4; }   // 32 rows x 16 k
    else            { arow = tid >> 3; acol = (tid & 7) * 4; }   // 16 k x 32 m
    bool aload = (tid < 128);
    int brow = tid >> 4, bcol = (tid & 15) * 4;                  // 16 k x 64 n

    float4 av, bv;
    if (aload) {
        if (AMODE == 0) av = *(const float4*)(Ab + (long)(m0 + arow) * Kdim + acol);
        else            av = *(const float4*)(Ab + (long)arow * Mdim + m0 + acol);
    }
    bv = *(const float4*)(Bb + (long)brow * Ndim + n0 + bcol);

    for (int k0 = 0; k0 < Kdim; k0 += BK) {
        __syncthreads();
        if (aload) {
            if (AMODE == 0) {
                As[acol + 0][arow] = av.x; As[acol + 1][arow] = av.y;
                As[acol + 2][arow] = av.z; As[acol + 3][arow] = av.w;
            } else {
                *(float4*)&As[arow][acol] = av;
            }
        }
        *(float4*)&Bs[brow][bcol] = bv;
        float4 av2, bv2;
        if (k0 + BK < Kdim) {
            int k1 = k0 + BK;
            if (aload) {
                if (AMODE == 0) av2 = *(const float4*)(Ab + (long)(m0 + arow) * Kdim + k1 + acol);
                else            av2 = *(const float4*)(Ab + (long)(k1 + arow) * Mdim + m0 + acol);
            }
            bv2 = *(const float4*)(Bb + (long)(k1 + brow) * Ndim + n0 + bcol);
        }
        __syncthreads();
        #pragma unroll
        for (int k = 0; k < BK; ++k) {
            float a0 = As[k][ty * 2], a1 = As[k][ty * 2 + 1];
            float4 b4 = *(const float4*)&Bs[k][tx * 4];
            float bb[4] = {b4.x, b4.y, b4.z, b4.w};
            #pragma unroll
            for (int j = 0; j < 4; ++j) {
                acc[0][j] += a0 * bb[j];
                acc[1][j] += a1 * bb[j];
            }
        }
        av = av2; bv = bv2;
    }

    int r0 = m0 + ty * 2, c0 = n0 + tx * 4;
    const float* Db = Dp + (long)b * sD;
    float* Cb = C + (long)b * sC;
    #pragma unroll
    for (int i = 0; i < 2; ++i) {
        float4 d = *(const float4*)(Db + (long)(r0 + i) * Ndim + c0);
        float pre[4] = {acc[i][0] + d.x, acc[i][1] + d.y,
                        acc[i][2] + d.z, acc[i][3] + d.w};
        *(float4*)(Cb + (long)(r0 + i) * Ndim + c0) =
            make_float4(fmaxf(pre[0], 0.f), fmaxf(pre[1], 0.f),
                        fmaxf(pre[2], 0.f), fmaxf(pre[3], 0.f));
    }
}

// ---------------------------------------------------------------------------
// Scores GEMM with fused masked-max epilogue (128x128 tile, 8x8/thr).
// ---------------------------------------------------------------------------
__global__ __launch_bounds__(256) void score_gemm(
    const float* __restrict__ A, const float* __restrict__ Bm,
    float* __restrict__ C, const int* __restrict__ len,
    unsigned* __restrict__ cu)
{
    int b = blockIdx.z;
    const float* Ab = A + (long)b * HSTR;
    const float* Bb = Bm + (long)b * HSTR;
    int m0 = blockIdx.x * 128, n0 = blockIdx.y * 128;
    int tid = threadIdx.x, tx = tid & 15, ty = tid >> 4;
    __shared__ float As[8][132];
    __shared__ float Bs[8][132];
    float acc[8][8] = {};
    int row = tid >> 1, kq = (tid & 1) << 2;
    float4 av = *(const float4*)(Ab + (long)(m0 + row) * DH + kq);
    float4 bv = *(const float4*)(Bb + (long)(n0 + row) * DH + kq);
    for (int kc = 0; kc < DH; kc += 8) {
        __syncthreads();
        As[kq + 0][row] = av.x; As[kq + 1][row] = av.y;
        As[kq + 2][row] = av.z; As[kq + 3][row] = av.w;
        Bs[kq + 0][row] = bv.x; Bs[kq + 1][row] = bv.y;
        Bs[kq + 2][row] = bv.z; Bs[kq + 3][row] = bv.w;
        float4 av2, bv2;
        if (kc + 8 < DH) {
            av2 = *(const float4*)(Ab + (long)(m0 + row) * DH + kc + 8 + kq);
            bv2 = *(const float4*)(Bb + (long)(n0 + row) * DH + kc + 8 + kq);
        }
        __syncthreads();
        #pragma unroll
        for (int k = 0; k < 8; ++k) {
            float a[8], bb[8];
            *(float4*)&a[0] = *(float4*)&As[k][ty * 8];
            *(float4*)&a[4] = *(float4*)&As[k][ty * 8 + 4];
            *(float4*)&bb[0] = *(float4*)&Bs[k][tx * 8];
            *(float4*)&bb[4] = *(float4*)&Bs[k][tx * 8 + 4];
            #pragma unroll
            for (int i = 0; i < 8; ++i)
                #pragma unroll
                for (int j = 0; j < 8; ++j) acc[i][j] += a[i] * bb[j];
        }
        av = av2; bv = bv2;
    }
    int L = len[b];
    float vmax = -3.0e38f;
    float* Cb = C + (long)b * SSTR;
    #pragma unroll
    for (int i = 0; i < 8; ++i) {
        int h = m0 + ty * 8 + i;
        bool hok = (h <= L);
        *(float4*)(Cb + (long)h * NN_ + n0 + tx * 8) =
            make_float4(acc[i][0], acc[i][1], acc[i][2], acc[i][3]);
        *(float4*)(Cb + (long)h * NN_ + n0 + tx * 8 + 4) =
            make_float4(acc[i][4], acc[i][5], acc[i][6], acc[i][7]);
        #pragma unroll
        for (int j = 0; j < 8; ++j) {
            int m = n0 + tx * 8 + j;
            if (hok && m >= 1 && m <= L && m != h) vmax = fmaxf(vmax, acc[i][j]);
        }
    }
    __syncthreads();
    float* red = &As[0][0];
    red[tid] = vmax; __syncthreads();
    for (int off = 128; off; off >>= 1) {
        if (tid < off) red[tid] = fmaxf(red[tid], red[tid + off]);
        __syncthreads();
    }
    if (tid == 0) atomicMax(&cu[b], f2mono(red[0]));
}

// --------------------------- small helpers ---------------------------------
__global__ void zero_scal(float* scal) {
    if (threadIdx.x < 96) scal[threadIdx.x] = 0.f;
}

// Lean column sums (grid (32,8)).
__global__ __launch_bounds__(256) void colsum_k(const float* __restrict__ sc,
                                                const int* __restrict__ len,
                                                const unsigned* __restrict__ cu,
                                                float* __restrict__ colsum)
{
    int b = blockIdx.x, yb = blockIdx.y;   // (32, 8)
    int tid = threadIdx.x, lane = tid & 63, w = tid >> 6;
    int L = len[b];
    float c = mono2f(cu[b]);
    int m = yb * 64 + lane;
    const float* S = sc + (long)b * SSTR;
    float s = 0.f;
    bool mv = (m >= 1 && m <= L);
    if (mv) {
        for (int h = 1 + w; h < NN_; h += 4) {
            if (h <= L && h != m) s += expf(S[(long)h * NN_ + m] - c);
        }
    }
    __shared__ float part[4][64];
    part[w][lane] = s; __syncthreads();
    if (tid < 64)
        colsum[(long)b * NN_ + yb * 64 + tid] =
            part[0][tid] + part[1][tid] + part[2][tid] + part[3][tid];
}

// ---------------------------------------------------------------------------
// Diag-0 build + inversion, DUAL-BATCH (512 thr, grid (16)): group g=tid>>8
// handles batch 2*blk+g with its own LDS slice. Both groups run the
// identical 16-stage invert128 loop -> barriers align; 2 waves/SIMD hides
// the serial chain's LDS/shuffle latency (was 67us at 1 wave/SIMD).
// ---------------------------------------------------------------------------
__global__ __launch_bounds__(512) void build_diag0(const float* __restrict__ sc,
                                                   const int* __restrict__ len,
                                                   const unsigned* __restrict__ cu,
                                                   const float* __restrict__ colsum,
                                                   float* __restrict__ Lm,
                                                   float* __restrict__ logdet)
{
    __shared__ float sm[2][6][8][132];
    int grp = threadIdx.x >> 8;
    int tid = threadIdx.x & 255;
    int b = blockIdx.x * 2 + grp;
    int L = len[b];
    float c = mono2f(cu[b]);
    const float* S = sc + (long)b * SSTR;
    const float* cs = colsum + (long)b * NN_;
    int tx = tid & 15, ty = tid >> 4;
    float r[8][8];
    #pragma unroll
    for (int i = 0; i < 8; ++i) {
        int gi = ty * 8 + i;
        #pragma unroll
        for (int j = 0; j < 8; ++j) {
            int gj = tx * 8 + j;
            int tm = gj + 1;
            bool mv = (tm <= L);
            float v;
            if (gi == 0) {
                v = mv ? expf(S[tm] - c) : 0.f;
            } else if (gi == gj) {
                float rv = mv ? expf(S[tm] - c) : 0.f;
                v = rv + cs[tm] + (mv ? 0.f : 1.f);
            } else {
                int h = gi + 1;
                v = (h <= L && mv) ? -expf(S[(long)h * NN_ + tm] - c) : 0.f;
            }
            r[i][j] = v;
        }
    }
    float lacc = invert128(r, tid,
                           (float(*)[8][132])&sm[grp][0],
                           (float(*)[8][132])&sm[grp][2],
                           (float(*)[8][132])&sm[grp][4]);
    float* Ab = Lm + (long)b * LSTR;
    #pragma unroll
    for (int i = 0; i < 8; ++i) {
        *(float4*)(Ab + (long)(ty * 8 + i) * 512 + tx * 8) =
            make_float4(r[i][0], r[i][1], r[i][2], r[i][3]);
        *(float4*)(Ab + (long)(ty * 8 + i) * 512 + tx * 8 + 4) =
            make_float4(r[i][4], r[i][5], r[i][6], r[i][7]);
    }
    if (tid == 0) atomicAdd(&logdet[b], lacc);
}

// ---------------------------------------------------------------------------
// LEAN build of the padded 512x512 Lhat (grid (32,64), 8 rows/block).
// ---------------------------------------------------------------------------
__global__ __launch_bounds__(256) void build_rows(const float* __restrict__ sc,
                                                  const int* __restrict__ len,
                                                  const unsigned* __restrict__ cu,
                                                  const float* __restrict__ colsum,
                                                  float* __restrict__ Lm,
                                                  float* __restrict__ Fb0)
{
    int b = blockIdx.x;
    int tid = threadIdx.x;
    int L = len[b];
    float c = mono2f(cu[b]);
    const float* S = sc + (long)b * SSTR;
    const float* cs = colsum + (long)b * NN_;

    int i0 = blockIdx.y * 8;
    #pragma unroll
    for (int r = 0; r < 8; ++r) {
        int i = i0 + r;
        float* Lrow = Lm + (long)b * LSTR + (long)i * 512;
        float* Frow = Fb0 + (long)b * HSTR + (long)i * 128;
        #pragma unroll
        for (int q = 0; q < 2; ++q) {
            int j = tid + q * 256;
            float v;
            if (i == 511 || j == 511) {
                v = (i == j) ? 1.f : 0.f;
            } else {
                int tm = j + 1;
                bool mv = (tm <= L);
                if (i == 0) {
                    v = mv ? expf(S[tm] - c) : 0.f;
                } else if (i == j) {
                    float rv = mv ? expf(S[tm] - c) : 0.f;
                    v = rv + cs[tm] + ((tm > L) ? 1.f : 0.f);
                } else {
                    int h = i + 1;
                    v = (h <= L && mv) ? -expf(S[(long)h * NN_ + tm] - c) : 0.f;
                }
            }
            if (!(i < 128 && j < 128)) Lrow[j] = v;
            if (q == 0 && j < 128 && i >= 128) Frow[j] = v;
        }
    }
}

// ---------------------------------------------------------------------------
// Pivot-row panels, COLUMN-SPLIT: R_j = Dinv @ A[kb][jt] in place.
// Grid (32, 12). Dual-writes into Fnext slot kb when jt == kb+1.  (= R5)
// ---------------------------------------------------------------------------
__global__ __launch_bounds__(256) void gj_panel(float* __restrict__ Lm,
                                                float* __restrict__ Fnext, int kb)
{
    constexpr int BK = 16;
    __shared__ float Ds[BK][132];
    __shared__ float As2[BK][36];
    int b = blockIdx.x;
    int j = blockIdx.y >> 2;        // 0..2
    int cq = blockIdx.y & 3;        // 0..3
    int jt = j + (j >= kb);
    int c0 = cq * 32;
    int tid = threadIdx.x;
    int tx = tid & 7, ty = tid >> 3;     // ty 0..31 (rows), tx 0..7 (cols)
    float* base = Lm + (long)b * LSTR;
    const float* D = base + (long)(kb * 128) * 512 + kb * 128;   // Dinv, ld 512
    float* Aj = base + (long)(kb * 128) * 512 + jt * 128;        // ld 512
    int drow = tid >> 1, dk8 = (tid & 1) * 8;
    int akr = tid >> 3, acq4 = (tid & 7) * 4;
    bool aload = (akr < BK);
    float acc[4][4] = {};
    float4 dva = *(const float4*)(D + (long)drow * 512 + dk8);
    float4 dvb = *(const float4*)(D + (long)drow * 512 + dk8 + 4);
    float4 av;
    if (aload) av = *(const float4*)(Aj + (long)akr * 512 + c0 + acq4);
    for (int kc = 0; kc < 128; kc += BK) {
        __syncthreads();
        Ds[dk8 + 0][drow] = dva.x; Ds[dk8 + 1][drow] = dva.y;
        Ds[dk8 + 2][drow] = dva.z; Ds[dk8 + 3][drow] = dva.w;
        Ds[dk8 + 4][drow] = dvb.x; Ds[dk8 + 5][drow] = dvb.y;
        Ds[dk8 + 6][drow] = dvb.z; Ds[dk8 + 7][drow] = dvb.w;
        if (aload) *(float4*)&As2[akr][acq4] = av;
        float4 dva2, dvb2, av2;
        if (kc + BK < 128) {
            dva2 = *(const float4*)(D + (long)drow * 512 + kc + BK + dk8);
            dvb2 = *(const float4*)(D + (long)drow * 512 + kc + BK + dk8 + 4);
            if (aload) av2 = *(const float4*)(Aj + (long)(kc + BK + akr) * 512 + c0 + acq4);
        }
        __syncthreads();
        #pragma unroll
        for (int k = 0; k < BK; ++k) {
            float4 a4 = *(const float4*)&Ds[k][ty * 4];
            float4 b4 = *(const float4*)&As2[k][tx * 4];
            float a[4] = {a4.x, a4.y, a4.z, a4.w};
            float bb[4] = {b4.x, b4.y, b4.z, b4.w};
            #pragma unroll
            for (int i = 0; i < 4; ++i)
                #pragma unroll
                for (int jj = 0; jj < 4; ++jj)
                    acc[i][jj] += a[i] * bb[jj];
        }
        dva = dva2; dvb = dvb2; av = av2;
    }
    bool dual = (jt == kb + 1);
    float* Fn = Fnext + (long)b * HSTR + (long)(kb * 128) * 128;
    #pragma unroll
    for (int i = 0; i < 4; ++i) {
        float4 o = make_float4(acc[i][0], acc[i][1], acc[i][2], acc[i][3]);
        *(float4*)(Aj + (long)(ty * 4 + i) * 512 + c0 + tx * 4) = o;
        if (dual) *(float4*)(Fn + (long)(ty * 4 + i) * 128 + c0 + tx * 4) = o;
    }
}

// ---------------------------------------------------------------------------
// LEAN trailing update: 64x128 half-tiles only (grid (32,3,8), 8x4 acc,
// BK=16). UNIFORM — no worker branch, no diag-skip. Low VGPR/LDS.
// A[ib][jt] -= F_ib @ R_jt  (jt==kb: A[ib][kb] = -F_ib @ Dinv).
// Dual-writes column kb+1 halves into Fnext.
// ---------------------------------------------------------------------------
__global__ __launch_bounds__(256) void gj_update64(
    float* __restrict__ Lm, const float* __restrict__ Fbuf,
    float* __restrict__ Fnext, int kb)
{
    constexpr int BK = 16;
    __shared__ float Fs[BK][68];
    __shared__ float Rs[BK][132];
    int b = blockIdx.x;
    int tid = threadIdx.x;
    float* base = Lm + (long)b * LSTR;
    int it = blockIdx.y;            // 0..2
    int ib = it + (it >= kb);
    int sub = blockIdx.z;           // 0..7
    int jt = sub >> 1;
    int half = sub & 1;
    int r0 = half * 64;
    int tx = tid & 31, ty = tid >> 5;    // 32 col-groups x 8 row-groups
    const float* F = Fbuf + (long)b * HSTR + (long)(ib * 128 + r0) * 128;  // ld 128
    const float* R = base + (long)(kb * 128) * 512 + (long)jt * 128;       // ld 512
    float* Cb = base + (long)(ib * 128 + r0) * 512 + jt * 128;
    int frow = tid >> 2, fkq = (tid & 3) << 2;   // F half: 64 rows x 16 k
    int rkr = tid >> 4, rcq = (tid & 15) << 3;   // R tile: 16 k x 128 cols
    float acc[8][4] = {};
    float4 fv  = *(const float4*)(F + (long)frow * 128 + fkq);
    float4 rva = *(const float4*)(R + (long)rkr * 512 + rcq);
    float4 rvb = *(const float4*)(R + (long)rkr * 512 + rcq + 4);
    for (int kc = 0; kc < 128; kc += BK) {
        __syncthreads();
        Fs[fkq + 0][frow] = fv.x; Fs[fkq + 1][frow] = fv.y;
        Fs[fkq + 2][frow] = fv.z; Fs[fkq + 3][frow] = fv.w;
        *(float4*)&Rs[rkr][rcq] = rva;
        *(float4*)&Rs[rkr][rcq + 4] = rvb;
        float4 fv2, rva2, rvb2;
        if (kc + BK < 128) {
            fv2  = *(const float4*)(F + (long)frow * 128 + kc + BK + fkq);
            rva2 = *(const float4*)(R + (long)(kc + BK + rkr) * 512 + rcq);
            rvb2 = *(const float4*)(R + (long)(kc + BK + rkr) * 512 + rcq + 4);
        }
        __syncthreads();
        #pragma unroll
        for (int k = 0; k < BK; ++k) {
            float a[8], bb[4];
            *(float4*)&a[0] = *(const float4*)&Fs[k][ty * 8];
            *(float4*)&a[4] = *(const float4*)&Fs[k][ty * 8 + 4];
            *(float4*)&bb[0] = *(const float4*)&Rs[k][tx * 4];
            #pragma unroll
            for (int i = 0; i < 8; ++i)
                #pragma unroll
                for (int j = 0; j < 4; ++j)
                    acc[i][j] += a[i] * bb[j];
        }
        fv = fv2; rva = rva2; rvb = rvb2;
    }
    bool dual = (jt == kb + 1);
    float* Fn = Fnext + (long)b * HSTR + (long)(ib * 128 + r0) * 128;
    if (jt == kb) {
        #pragma unroll
        for (int i = 0; i < 8; ++i)
            *(float4*)(Cb + (long)(ty * 8 + i) * 512 + tx * 4) =
                make_float4(-acc[i][0], -acc[i][1], -acc[i][2], -acc[i][3]);
    } else {
        #pragma unroll
        for (int i = 0; i < 8; ++i) {
            float4 o = *(const float4*)(Cb + (long)(ty * 8 + i) * 512 + tx * 4);
            o = make_float4(o.x - acc[i][0], o.y - acc[i][1],
                            o.z - acc[i][2], o.w - acc[i][3]);
            *(float4*)(Cb + (long)(ty * 8 + i) * 512 + tx * 4) = o;
            if (dual) *(float4*)(Fn + (long)(ty * 8 + i) * 128 + tx * 4) = o;
        }
    }
}

// ---------------------------------------------------------------------------
// Standalone trailing-diag inversion, DUAL-BATCH (512 thr, grid (16)):
// group g handles batch 2*blk+g, own LDS slice, aligned barriers.
// 2 waves/SIMD -> latency of the serial 16-stage chain is half-hidden.
// ---------------------------------------------------------------------------
__global__ __launch_bounds__(512) void inv_k(float* __restrict__ Lm,
                                             float* __restrict__ logdet, int kb)
{
    __shared__ float sm[2][6][8][132];
    int grp = threadIdx.x >> 8;
    int tid = threadIdx.x & 255;
    int b = blockIdx.x * 2 + grp;
    int tx = tid & 15, ty = tid >> 4;
    float* Dd = Lm + (long)b * LSTR + (long)(kb * 128) * 512 + kb * 128;
    float r[8][8];
    #pragma unroll
    for (int i = 0; i < 8; ++i) {
        *(float4*)&r[i][0] = *(const float4*)(Dd + (long)(ty * 8 + i) * 512 + tx * 8);
        *(float4*)&r[i][4] = *(const float4*)(Dd + (long)(ty * 8 + i) * 512 + tx * 8 + 4);
    }
    float lacc = invert128(r, tid,
                           (float(*)[8][132])&sm[grp][0],
                           (float(*)[8][132])&sm[grp][2],
                           (float(*)[8][132])&sm[grp][4]);
    #pragma unroll
    for (int i = 0; i < 8; ++i) {
        *(float4*)(Dd + (long)(ty * 8 + i) * 512 + tx * 8) =
            make_float4(r[i][0], r[i][1], r[i][2], r[i][3]);
        *(float4*)(Dd + (long)(ty * 8 + i) * 512 + tx * 8 + 4) =
            make_float4(r[i][4], r[i][5], r[i][6], r[i][7]);
    }
    if (tid == 0) atomicAdd(&logdet[b], lacc);
}

// --------------------------- marginals Y + entropy partials -----------------
__global__ __launch_bounds__(256) void y_k(const float* __restrict__ sc,
                                           const float* __restrict__ Binv,
                                           const int* __restrict__ len,
                                           const unsigned* __restrict__ cu,
                                           float* __restrict__ Y,
                                           float* __restrict__ Ssum)
{
    int b = blockIdx.x;
    int ht = blockIdx.y >> 3, mt = blockIdx.y & 7;
    int h0 = ht * 64, m0 = mt * 64;
    int tid = threadIdx.x;
    int L = len[b];
    float c = mono2f(cu[b]);
    const float* S = sc + (long)b * SSTR;
    const float* Bi = Binv + (long)b * LSTR;
    float* Yb = Y + (long)b * SSTR;
    __shared__ float Bs[64][65];
    __shared__ float Ds[64], C0s[64];
    {
        int hh = tid & 63, m4 = tid >> 6;
        int col = h0 + hh - 1;
        for (int mm = m4; mm < 64; mm += 4) {
            int row = m0 + mm - 1;
            Bs[mm][hh] = (row >= 0 && col >= 0) ? Bi[(long)row * 512 + col] : 0.f;
        }
    }
    if (tid < 64) {
        int row = m0 + tid - 1;
        Ds[tid] = (row >= 0) ? Bi[(long)row * 512 + row] : 0.f;
    } else if (tid < 128) {
        int mm = tid - 64, row = m0 + mm - 1;
        C0s[mm] = (row >= 0) ? Bi[(long)row * 512] : 0.f;
    }
    __syncthreads();
    int mm = tid & 63, hq = tid >> 6;
    int m = m0 + mm;
    float lsum = 0.f;
    bool mvalid = (m >= 1 && m <= L);
    float dterm = (m >= 2) ? Ds[mm] : 0.f;
    #pragma unroll
    for (int hi = 0; hi < 16; ++hi) {
        int hh = hq * 16 + hi;
        int h = h0 + hh;
        float s = S[(long)h * NN_ + m];
        float y = 0.f;
        if (mvalid && h <= L && h != m) {
            float a = expf(s - c);
            float g;
            if (h == 0) g = C0s[mm] + dterm;
            else g = dterm - ((h >= 2) ? Bs[mm][hh] : 0.f);
            y = a * g;
        }
        Yb[(long)h * NN_ + m] = y;
        lsum += y * s;
    }
    __shared__ float red[256];
    red[tid] = lsum; __syncthreads();
    for (int off = 128; off; off >>= 1) {
        if (tid < off) red[tid] += red[tid + off];
        __syncthreads();
    }
    if (tid == 0) atomicAdd(&Ssum[b], red[0]);
}

// finalize + re-zero accumulators for the next iteration
__global__ void fin_k(const int* __restrict__ len, unsigned* __restrict__ cu,
                      float* __restrict__ logdet, float* __restrict__ Ssum,
                      float* __restrict__ outLogZ, float* __restrict__ outEntr)
{
    int b = threadIdx.x;
    if (b < 32) {
        float c = mono2f(cu[b]);
        float lz = logdet[b] + (float)len[b] * c;
        outLogZ[b] = lz;
        outEntr[b] = lz - Ssum[b];
        cu[b] = 0u;
        logdet[b] = 0.f;
        Ssum[b] = 0.f;
    }
}

// ---------------------------------------------------------------------------
extern "C" void kernel_launch(void* const* d_in, const int* in_sizes, int n_in,
                              void* d_out, int out_size, void* d_ws, size_t ws_size,
                              hipStream_t stream)
{
    const float* Xh = (const float*)d_in[0];
    const float* Xm = (const float*)d_in[1];
    const int*   len = (const int*)d_in[2];
    const float* Wh = (const float*)d_in[3];
    const float* bh = (const float*)d_in[4];
    const float* Wm = (const float*)d_in[5];
    const float* bm = (const float*)d_in[6];
    const float* V  = (const float*)d_in[7];

    float* ws = (float*)d_ws;
    constexpr long U = 2097152;           // 32*512*128
    float* H0 = ws;
    float* M0 = ws + U;
    float* Ha = ws + 2 * U;
    float* Ma = ws + 3 * U;
    float* Hb = ws + 4 * U;
    float* Mb = ws + 5 * U;
    float* T1 = ws + 6 * U;               // P = H@V (live across GJ!)
    float* Yt = ws + 7 * U;               // Q scratch (feedback) / Fbuf ping (GJ)
    float* Lm = ws + 8 * U;               // 32 x 512 x 512
    float* cs = ws + 12 * U;              // colsum 32*512
    float* scal = ws + 12 * U + 16384;    // c_u[32] | logdet[32] | Ssum[32]
    unsigned* cu = (unsigned*)scal;
    float* logdet = scal + 32;
    float* Ssum = scal + 64;

    float* Sout = (float*)d_out;                        // scores  [32,512,512]
    float* outLogZ = (float*)d_out + 8388608;           // logZ    [32]
    float* Yout = (float*)d_out + 8388640;              // Y       [32,512,512]
    float* outEntr = (float*)d_out + 8388640 + 8388608; // entr    [32]

    zero_scal<<<1, 96, 0, stream>>>(scal);

    // H0 = Xh@Wh^T + bh ; H = relu(H0)   (and same for M)
    gemm64<0,1,1><<<dim3(256, 2, 1), 256, 0, stream>>>(
        Xh, Wh, Ha, bh, H0, 16384, DH, DIN, 0, 0, 0, 0);
    gemm64<0,1,1><<<dim3(256, 2, 1), 256, 0, stream>>>(
        Xm, Wm, Ma, bm, M0, 16384, DH, DIN, 0, 0, 0, 0);

    float* Hc = Ha; float* Mc = Ma; float* Hn = Hb; float* Mn = Mb;
    for (int t = 0; t < NITER; ++t) {
        if (t > 0) {
            // Q = Mc @ V^T (Yt); Hn = relu(H0 + Y@Q); Mn = relu(M0 + Y^T@P)
            gemm64<0,1,0><<<dim3(8,2,BB),256,0,stream>>>(
                Mc, V, Yt, nullptr, nullptr, 512, DH, DH, HSTR, 0, HSTR, 0);
            gemm32<0><<<dim3(16,2,BB),256,0,stream>>>(
                Yout, Yt, Hn, H0, 512, DH, 512, SSTR, HSTR, HSTR, HSTR);
            gemm32<1><<<dim3(16,2,BB),256,0,stream>>>(
                Yout, T1, Mn, M0, 512, DH, 512, SSTR, HSTR, HSTR, HSTR);
            { float* tmp = Hc; Hc = Hn; Hn = tmp; }
            { float* tmp = Mc; Mc = Mn; Mn = tmp; }
        }
        // P = Hc @ V (T1, persists to next feedback); scores = P @ Mc^T
        gemm64<0,0,0><<<dim3(8,2,BB),256,0,stream>>>(
            Hc, V, T1, nullptr, nullptr, 512, DH, DH, HSTR, 0, HSTR, 0);
        score_gemm<<<dim3(4,4,BB),256,0,stream>>>(T1, Mc, Sout, len, cu);

        // colsum -> diag-0 build+invert (dual-batch) -> lean streaming build
        colsum_k<<<dim3(BB,8),256,0,stream>>>(Sout, len, cu, cs);
        build_diag0<<<dim3(BB/2),512,0,stream>>>(Sout, len, cu, cs, Lm, logdet);
        build_rows<<<dim3(BB,64),256,0,stream>>>(Sout, len, cu, cs, Lm, Yt);

        // Fbuf ping-pong: even kb reads Yt, writes Hn (dead during GJ); odd flips
        float* Fbufs[2] = {Yt, Hn};
        for (int kb = 0; kb < 4; ++kb) {
            float* Fcur  = Fbufs[kb & 1];
            float* Fnext = Fbufs[(kb + 1) & 1];
            gj_panel<<<dim3(BB,12),256,0,stream>>>(Lm, Fnext, kb);
            gj_update64<<<dim3(BB,3,8),256,0,stream>>>(Lm, Fcur, Fnext, kb);
            if (kb < 3)
                inv_k<<<dim3(BB/2),512,0,stream>>>(Lm, logdet, kb + 1);
        }
        y_k<<<dim3(BB,64),256,0,stream>>>(Sout, Lm, len, cu, Yout, Ssum);
        fin_k<<<1,32,0,stream>>>(len, cu, logdet, Ssum, outLogZ, outEntr);
    }
}

// Round 12
// 5417.956 us; speedup vs baseline: 1.2032x; 1.2032x over previous
//
#include <hip/hip_runtime.h>
#include <math.h>

constexpr int BB = 32;     // batch
constexpr int NN_ = 512;   // sequence length
constexpr int DIN = 256;
constexpr int DH = 128;
constexpr int NITER = 10;
constexpr long HSTR = (long)NN_ * DH;    // 65536
constexpr long SSTR = (long)NN_ * NN_;   // 262144
constexpr long LSTR = 512L * 512L;       // 262144

__device__ __forceinline__ unsigned f2mono(float f) {
    unsigned u = __float_as_uint(f);
    return (u & 0x80000000u) ? ~u : (u | 0x80000000u);
}
__device__ __forceinline__ float mono2f(unsigned u) {
    return __uint_as_float((u & 0x80000000u) ? (u & 0x7fffffffu) : ~u);
}

// ---------------------------------------------------------------------------
// 128x128 in-register block-GJ inversion, 512-THREAD variant (8 waves on one
// problem -> 2 waves/SIMD hide the serial chain's LDS/shuffle latency).
// r[4][8] per thread: rows ty*4..ty*4+3 (ty=tid>>4, 0..31), cols tx*8..+7.
// RowP/ColPT/Rnew contents, pivot shuffle chain, Rnew writer (waves 0..3,
// identical to the 256-thr version's tid<256), and every per-element FMA
// chain are BIT-IDENTICAL to the verified 256-thread invert128.
// Opens with __syncthreads().
// ---------------------------------------------------------------------------
__device__ __forceinline__ float invert128_w8(float r[4][8], int tid,
        float (*RowP)[8][132], float (*ColPT)[8][132], float (*Rnew)[8][132])
{
    int tx = tid & 15, ty = tid >> 4;      // ty 0..31
    int lane = tid & 63, w = tid >> 6;     // w 0..7
    int li = lane >> 3, lj = lane & 7;
    float lacc = 0.f;
    __syncthreads();
    for (int s8 = 0; s8 < 16; ++s8) {
        int p = s8 & 1;
        if ((ty >> 1) == s8) {
            // pivot row-block rows s8*8..+7: local row = (ty&1)*4 + i
            #pragma unroll
            for (int i = 0; i < 4; ++i)
                #pragma unroll
                for (int j = 0; j < 8; ++j)
                    RowP[p][(ty & 1) * 4 + i][tx * 8 + j] = r[i][j];
        }
        if (tx == s8) {
            // pivot col-block: identity subtracted on global diagonal
            #pragma unroll
            for (int i = 0; i < 4; ++i) {
                int grow = ty * 4 + i;
                #pragma unroll
                for (int j = 0; j < 8; ++j) {
                    float sub = (grow == s8 * 8 + j) ? 1.f : 0.f;
                    ColPT[p][j][grow] = r[i][j] - sub;
                }
            }
        }
        __syncthreads();
        // all waves: invert 8x8 pivot block via shuffles (wave-redundant)
        float d = RowP[p][li][s8 * 8 + lj];
        float prod = 1.f;
        #pragma unroll
        for (int s = 0; s < 8; ++s) {
            float pv = __shfl(d, s * 9);
            prod *= pv;
            float pinv = 1.0f / pv;
            float rv = __shfl(d, s * 8 + lj);
            float cv = __shfl(d, li * 8 + s);
            float nd;
            if (li == s && lj == s)  nd = pinv;
            else if (li == s)        nd = rv * pinv;
            else if (lj == s)        nd = -cv * pinv;
            else                     nd = d - cv * pinv * rv;
            d = nd;
        }
        lacc += logf(fabsf(prod));
        // Rnew = Dinv @ RowP (waves 0..3 only — identical to 256-thr path);
        // pivot-col slice overwritten with I + Dinv
        if (w < 4) {
            int sr = li;
            int jq = w * 32 + lj * 4;
            float dsr[8];
            #pragma unroll
            for (int t = 0; t < 8; ++t) dsr[t] = __shfl(d, (lane & 56) + t);
            float a0 = 0.f, a1 = 0.f, a2 = 0.f, a3 = 0.f;
            #pragma unroll
            for (int t = 0; t < 8; ++t) {
                float4 rp = *(const float4*)&RowP[p][t][jq];
                a0 += dsr[t] * rp.x; a1 += dsr[t] * rp.y;
                a2 += dsr[t] * rp.z; a3 += dsr[t] * rp.w;
            }
            if ((jq >> 3) == s8) {
                if ((jq & 7) == 0) {
                    a0 = dsr[0] + ((sr == 0) ? 1.f : 0.f);
                    a1 = dsr[1] + ((sr == 1) ? 1.f : 0.f);
                    a2 = dsr[2] + ((sr == 2) ? 1.f : 0.f);
                    a3 = dsr[3] + ((sr == 3) ? 1.f : 0.f);
                } else {
                    a0 = dsr[4] + ((sr == 4) ? 1.f : 0.f);
                    a1 = dsr[5] + ((sr == 5) ? 1.f : 0.f);
                    a2 = dsr[6] + ((sr == 6) ? 1.f : 0.f);
                    a3 = dsr[7] + ((sr == 7) ? 1.f : 0.f);
                }
            }
            *(float4*)&Rnew[p][sr][jq] = make_float4(a0, a1, a2, a3);
        }
        __syncthreads();
        // uniform branch-free update: r -= ColPT^T @ Rnew (4 rows/thread)
        #pragma unroll
        for (int t = 0; t < 8; ++t) {
            float cp[4], rn[8];
            *(float4*)&cp[0] = *(const float4*)&ColPT[p][t][ty * 4];
            *(float4*)&rn[0] = *(const float4*)&Rnew[p][t][tx * 8];
            *(float4*)&rn[4] = *(const float4*)&Rnew[p][t][tx * 8 + 4];
            #pragma unroll
            for (int i = 0; i < 4; ++i)
                #pragma unroll
                for (int j = 0; j < 8; ++j)
                    r[i][j] -= cp[i] * rn[j];
        }
        // no trailing barrier: panels double-buffered
    }
    return lacc;
}

// ---------------------------------------------------------------------------
// Generic fp32 tiled GEMM (64x64 tile, BK=16, 4x4/thread), prefetched.
// ---------------------------------------------------------------------------
template<int AMODE, int BMODE, int EPI>
__global__ __launch_bounds__(256) void gemm64(
    const float* __restrict__ A, const float* __restrict__ Bm,
    float* __restrict__ C, const float* __restrict__ Dp, float* __restrict__ C2,
    int Mdim, int Ndim, int Kdim,
    long sA, long sB, long sC, long sD)
{
    constexpr int BK = 16;
    __shared__ float As[BK][64 + 4];
    __shared__ float Bs[BK][64 + 4];
    int b = blockIdx.z;
    const float* Ab = A + (long)b * sA;
    const float* Bb = Bm + (long)b * sB;
    int m0 = blockIdx.x * 64, n0 = blockIdx.y * 64;
    int tid = threadIdx.x;
    int tx = tid & 15, ty = tid >> 4;
    float acc[4][4] = {};

    int arow, acol, brow, bcol;
    if (AMODE == 0) { arow = tid >> 2; acol = (tid & 3) * 4; }
    else            { arow = tid >> 4; acol = (tid & 15) * 4; }
    if (BMODE == 0) { brow = tid >> 4; bcol = (tid & 15) * 4; }
    else            { brow = tid >> 2; bcol = (tid & 3) * 4; }

    float4 av, bv;
    if (AMODE == 0) av = *(const float4*)(Ab + (long)(m0 + arow) * Kdim + acol);
    else            av = *(const float4*)(Ab + (long)(0 + arow) * Mdim + m0 + acol);
    if (BMODE == 0) bv = *(const float4*)(Bb + (long)(0 + brow) * Ndim + n0 + bcol);
    else            bv = *(const float4*)(Bb + (long)(n0 + brow) * Kdim + bcol);

    for (int k0 = 0; k0 < Kdim; k0 += BK) {
        __syncthreads();
        if (AMODE == 0) {
            As[acol + 0][arow] = av.x; As[acol + 1][arow] = av.y;
            As[acol + 2][arow] = av.z; As[acol + 3][arow] = av.w;
        } else {
            *(float4*)&As[arow][acol] = av;
        }
        if (BMODE == 0) {
            *(float4*)&Bs[brow][bcol] = bv;
        } else {
            Bs[bcol + 0][brow] = bv.x; Bs[bcol + 1][brow] = bv.y;
            Bs[bcol + 2][brow] = bv.z; Bs[bcol + 3][brow] = bv.w;
        }
        float4 av2, bv2;
        if (k0 + BK < Kdim) {
            int k1 = k0 + BK;
            if (AMODE == 0) av2 = *(const float4*)(Ab + (long)(m0 + arow) * Kdim + k1 + acol);
            else            av2 = *(const float4*)(Ab + (long)(k1 + arow) * Mdim + m0 + acol);
            if (BMODE == 0) bv2 = *(const float4*)(Bb + (long)(k1 + brow) * Ndim + n0 + bcol);
            else            bv2 = *(const float4*)(Bb + (long)(n0 + brow) * Kdim + k1 + bcol);
        }
        __syncthreads();
        #pragma unroll
        for (int k = 0; k < BK; ++k) {
            float4 a4 = *(const float4*)&As[k][ty * 4];
            float4 b4 = *(const float4*)&Bs[k][tx * 4];
            float avv[4] = {a4.x, a4.y, a4.z, a4.w};
            float bvv[4] = {b4.x, b4.y, b4.z, b4.w};
            #pragma unroll
            for (int i = 0; i < 4; ++i)
                #pragma unroll
                for (int j = 0; j < 4; ++j)
                    acc[i][j] += avv[i] * bvv[j];
        }
        av = av2; bv = bv2;
    }

    int r0 = m0 + ty * 4, c0 = n0 + tx * 4;
    if (EPI == 0) {
        float* Cb = C + (long)b * sC;
        #pragma unroll
        for (int i = 0; i < 4; ++i)
            *(float4*)(Cb + (long)(r0 + i) * Ndim + c0) =
                make_float4(acc[i][0], acc[i][1], acc[i][2], acc[i][3]);
    } else if (EPI == 1) {
        float4 bias = *(const float4*)(Dp + c0);
        float bb4[4] = {bias.x, bias.y, bias.z, bias.w};
        #pragma unroll
        for (int i = 0; i < 4; ++i) {
            float pre[4];
            #pragma unroll
            for (int j = 0; j < 4; ++j) pre[j] = acc[i][j] + bb4[j];
            *(float4*)(C2 + (long)(r0 + i) * Ndim + c0) =
                make_float4(pre[0], pre[1], pre[2], pre[3]);
            *(float4*)(C + (long)(r0 + i) * Ndim + c0) =
                make_float4(fmaxf(pre[0], 0.f), fmaxf(pre[1], 0.f),
                            fmaxf(pre[2], 0.f), fmaxf(pre[3], 0.f));
        }
    } else {
        const float* Db = Dp + (long)b * sD;
        float* Cb = C + (long)b * sC;
        #pragma unroll
        for (int i = 0; i < 4; ++i) {
            float4 d = *(const float4*)(Db + (long)(r0 + i) * Ndim + c0);
            float pre[4] = {acc[i][0] + d.x, acc[i][1] + d.y,
                            acc[i][2] + d.z, acc[i][3] + d.w};
            *(float4*)(Cb + (long)(r0 + i) * Ndim + c0) =
                make_float4(fmaxf(pre[0], 0.f), fmaxf(pre[1], 0.f),
                            fmaxf(pre[2], 0.f), fmaxf(pre[3], 0.f));
        }
    }
}

// ---------------------------------------------------------------------------
// 32x64-tile fp32 GEMM for the K=512 feedback matmuls (C = relu(acc + D)).
// ---------------------------------------------------------------------------
template<int AMODE>
__global__ __launch_bounds__(256) void gemm32(
    const float* __restrict__ A, const float* __restrict__ Bm,
    float* __restrict__ C, const float* __restrict__ Dp,
    int Mdim, int Ndim, int Kdim,
    long sA, long sB, long sC, long sD)
{
    constexpr int BK = 16;
    __shared__ float As[BK][36];
    __shared__ float Bs[BK][68];
    int b = blockIdx.z;
    const float* Ab = A + (long)b * sA;
    const float* Bb = Bm + (long)b * sB;
    int m0 = blockIdx.x * 32, n0 = blockIdx.y * 64;
    int tid = threadIdx.x;
    int tx = tid & 15, ty = tid >> 4;
    float acc[2][4] = {};

    int arow, acol;
    if (AMODE == 0) { arow = tid >> 2; acol = (tid & 3) * 4; }   // 32 rows x 16 k
    else            { arow = tid >> 3; acol = (tid & 7) * 4; }   // 16 k x 32 m
    bool aload = (tid < 128);
    int brow = tid >> 4, bcol = (tid & 15) * 4;                  // 16 k x 64 n

    float4 av, bv;
    if (aload) {
        if (AMODE == 0) av = *(const float4*)(Ab + (long)(m0 + arow) * Kdim + acol);
        else            av = *(const float4*)(Ab + (long)arow * Mdim + m0 + acol);
    }
    bv = *(const float4*)(Bb + (long)brow * Ndim + n0 + bcol);

    for (int k0 = 0; k0 < Kdim; k0 += BK) {
        __syncthreads();
        if (aload) {
            if (AMODE == 0) {
                As[acol + 0][arow] = av.x; As[acol + 1][arow] = av.y;
                As[acol + 2][arow] = av.z; As[acol + 3][arow] = av.w;
            } else {
                *(float4*)&As[arow][acol] = av;
            }
        }
        *(float4*)&Bs[brow][bcol] = bv;
        float4 av2, bv2;
        if (k0 + BK < Kdim) {
            int k1 = k0 + BK;
            if (aload) {
                if (AMODE == 0) av2 = *(const float4*)(Ab + (long)(m0 + arow) * Kdim + k1 + acol);
                else            av2 = *(const float4*)(Ab + (long)(k1 + arow) * Mdim + m0 + acol);
            }
            bv2 = *(const float4*)(Bb + (long)(k1 + brow) * Ndim + n0 + bcol);
        }
        __syncthreads();
        #pragma unroll
        for (int k = 0; k < BK; ++k) {
            float a0 = As[k][ty * 2], a1 = As[k][ty * 2 + 1];
            float4 b4 = *(const float4*)&Bs[k][tx * 4];
            float bb[4] = {b4.x, b4.y, b4.z, b4.w};
            #pragma unroll
            for (int j = 0; j < 4; ++j) {
                acc[0][j] += a0 * bb[j];
                acc[1][j] += a1 * bb[j];
            }
        }
        av = av2; bv = bv2;
    }

    int r0 = m0 + ty * 2, c0 = n0 + tx * 4;
    const float* Db = Dp + (long)b * sD;
    float* Cb = C + (long)b * sC;
    #pragma unroll
    for (int i = 0; i < 2; ++i) {
        float4 d = *(const float4*)(Db + (long)(r0 + i) * Ndim + c0);
        float pre[4] = {acc[i][0] + d.x, acc[i][1] + d.y,
                        acc[i][2] + d.z, acc[i][3] + d.w};
        *(float4*)(Cb + (long)(r0 + i) * Ndim + c0) =
            make_float4(fmaxf(pre[0], 0.f), fmaxf(pre[1], 0.f),
                        fmaxf(pre[2], 0.f), fmaxf(pre[3], 0.f));
    }
}

// ---------------------------------------------------------------------------
// Scores GEMM with fused masked-max epilogue (128x128 tile, 8x8/thr).
// ---------------------------------------------------------------------------
__global__ __launch_bounds__(256) void score_gemm(
    const float* __restrict__ A, const float* __restrict__ Bm,
    float* __restrict__ C, const int* __restrict__ len,
    unsigned* __restrict__ cu)
{
    int b = blockIdx.z;
    const float* Ab = A + (long)b * HSTR;
    const float* Bb = Bm + (long)b * HSTR;
    int m0 = blockIdx.x * 128, n0 = blockIdx.y * 128;
    int tid = threadIdx.x, tx = tid & 15, ty = tid >> 4;
    __shared__ float As[8][132];
    __shared__ float Bs[8][132];
    float acc[8][8] = {};
    int row = tid >> 1, kq = (tid & 1) << 2;
    float4 av = *(const float4*)(Ab + (long)(m0 + row) * DH + kq);
    float4 bv = *(const float4*)(Bb + (long)(n0 + row) * DH + kq);
    for (int kc = 0; kc < DH; kc += 8) {
        __syncthreads();
        As[kq + 0][row] = av.x; As[kq + 1][row] = av.y;
        As[kq + 2][row] = av.z; As[kq + 3][row] = av.w;
        Bs[kq + 0][row] = bv.x; Bs[kq + 1][row] = bv.y;
        Bs[kq + 2][row] = bv.z; Bs[kq + 3][row] = bv.w;
        float4 av2, bv2;
        if (kc + 8 < DH) {
            av2 = *(const float4*)(Ab + (long)(m0 + row) * DH + kc + 8 + kq);
            bv2 = *(const float4*)(Bb + (long)(n0 + row) * DH + kc + 8 + kq);
        }
        __syncthreads();
        #pragma unroll
        for (int k = 0; k < 8; ++k) {
            float a[8], bb[8];
            *(float4*)&a[0] = *(float4*)&As[k][ty * 8];
            *(float4*)&a[4] = *(float4*)&As[k][ty * 8 + 4];
            *(float4*)&bb[0] = *(float4*)&Bs[k][tx * 8];
            *(float4*)&bb[4] = *(float4*)&Bs[k][tx * 8 + 4];
            #pragma unroll
            for (int i = 0; i < 8; ++i)
                #pragma unroll
                for (int j = 0; j < 8; ++j) acc[i][j] += a[i] * bb[j];
        }
        av = av2; bv = bv2;
    }
    int L = len[b];
    float vmax = -3.0e38f;
    float* Cb = C + (long)b * SSTR;
    #pragma unroll
    for (int i = 0; i < 8; ++i) {
        int h = m0 + ty * 8 + i;
        bool hok = (h <= L);
        *(float4*)(Cb + (long)h * NN_ + n0 + tx * 8) =
            make_float4(acc[i][0], acc[i][1], acc[i][2], acc[i][3]);
        *(float4*)(Cb + (long)h * NN_ + n0 + tx * 8 + 4) =
            make_float4(acc[i][4], acc[i][5], acc[i][6], acc[i][7]);
        #pragma unroll
        for (int j = 0; j < 8; ++j) {
            int m = n0 + tx * 8 + j;
            if (hok && m >= 1 && m <= L && m != h) vmax = fmaxf(vmax, acc[i][j]);
        }
    }
    __syncthreads();
    float* red = &As[0][0];
    red[tid] = vmax; __syncthreads();
    for (int off = 128; off; off >>= 1) {
        if (tid < off) red[tid] = fmaxf(red[tid], red[tid + off]);
        __syncthreads();
    }
    if (tid == 0) atomicMax(&cu[b], f2mono(red[0]));
}

// --------------------------- small helpers ---------------------------------
__global__ void zero_scal(float* scal) {
    if (threadIdx.x < 96) scal[threadIdx.x] = 0.f;
}

// Lean column sums (grid (32,8)).
__global__ __launch_bounds__(256) void colsum_k(const float* __restrict__ sc,
                                                const int* __restrict__ len,
                                                const unsigned* __restrict__ cu,
                                                float* __restrict__ colsum)
{
    int b = blockIdx.x, yb = blockIdx.y;   // (32, 8)
    int tid = threadIdx.x, lane = tid & 63, w = tid >> 6;
    int L = len[b];
    float c = mono2f(cu[b]);
    int m = yb * 64 + lane;
    const float* S = sc + (long)b * SSTR;
    float s = 0.f;
    bool mv = (m >= 1 && m <= L);
    if (mv) {
        for (int h = 1 + w; h < NN_; h += 4) {
            if (h <= L && h != m) s += expf(S[(long)h * NN_ + m] - c);
        }
    }
    __shared__ float part[4][64];
    part[w][lane] = s; __syncthreads();
    if (tid < 64)
        colsum[(long)b * NN_ + yb * 64 + tid] =
            part[0][tid] + part[1][tid] + part[2][tid] + part[3][tid];
}

// ---------------------------------------------------------------------------
// Diag-0 build + inversion (512 thr, grid (32)): one batch per block,
// 8 waves cooperating on ONE inversion (r[4][8]/thread).
// ---------------------------------------------------------------------------
__global__ __launch_bounds__(512) void build_diag0(const float* __restrict__ sc,
                                                   const int* __restrict__ len,
                                                   const unsigned* __restrict__ cu,
                                                   const float* __restrict__ colsum,
                                                   float* __restrict__ Lm,
                                                   float* __restrict__ logdet)
{
    __shared__ float sm[6][8][132];
    int b = blockIdx.x;
    int tid = threadIdx.x;
    int L = len[b];
    float c = mono2f(cu[b]);
    const float* S = sc + (long)b * SSTR;
    const float* cs = colsum + (long)b * NN_;
    int tx = tid & 15, ty = tid >> 4;   // ty 0..31
    float r[4][8];
    #pragma unroll
    for (int i = 0; i < 4; ++i) {
        int gi = ty * 4 + i;
        #pragma unroll
        for (int j = 0; j < 8; ++j) {
            int gj = tx * 8 + j;
            int tm = gj + 1;
            bool mv = (tm <= L);
            float v;
            if (gi == 0) {
                v = mv ? expf(S[tm] - c) : 0.f;
            } else if (gi == gj) {
                float rv = mv ? expf(S[tm] - c) : 0.f;
                v = rv + cs[tm] + (mv ? 0.f : 1.f);
            } else {
                int h = gi + 1;
                v = (h <= L && mv) ? -expf(S[(long)h * NN_ + tm] - c) : 0.f;
            }
            r[i][j] = v;
        }
    }
    float lacc = invert128_w8(r, tid,
                              (float(*)[8][132])&sm[0],
                              (float(*)[8][132])&sm[2],
                              (float(*)[8][132])&sm[4]);
    float* Ab = Lm + (long)b * LSTR;
    #pragma unroll
    for (int i = 0; i < 4; ++i) {
        *(float4*)(Ab + (long)(ty * 4 + i) * 512 + tx * 8) =
            make_float4(r[i][0], r[i][1], r[i][2], r[i][3]);
        *(float4*)(Ab + (long)(ty * 4 + i) * 512 + tx * 8 + 4) =
            make_float4(r[i][4], r[i][5], r[i][6], r[i][7]);
    }
    if (tid == 0) atomicAdd(&logdet[b], lacc);
}

// ---------------------------------------------------------------------------
// LEAN build of the padded 512x512 Lhat (grid (32,64), 8 rows/block).
// ---------------------------------------------------------------------------
__global__ __launch_bounds__(256) void build_rows(const float* __restrict__ sc,
                                                  const int* __restrict__ len,
                                                  const unsigned* __restrict__ cu,
                                                  const float* __restrict__ colsum,
                                                  float* __restrict__ Lm,
                                                  float* __restrict__ Fb0)
{
    int b = blockIdx.x;
    int tid = threadIdx.x;
    int L = len[b];
    float c = mono2f(cu[b]);
    const float* S = sc + (long)b * SSTR;
    const float* cs = colsum + (long)b * NN_;

    int i0 = blockIdx.y * 8;
    #pragma unroll
    for (int r = 0; r < 8; ++r) {
        int i = i0 + r;
        float* Lrow = Lm + (long)b * LSTR + (long)i * 512;
        float* Frow = Fb0 + (long)b * HSTR + (long)i * 128;
        #pragma unroll
        for (int q = 0; q < 2; ++q) {
            int j = tid + q * 256;
            float v;
            if (i == 511 || j == 511) {
                v = (i == j) ? 1.f : 0.f;
            } else {
                int tm = j + 1;
                bool mv = (tm <= L);
                if (i == 0) {
                    v = mv ? expf(S[tm] - c) : 0.f;
                } else if (i == j) {
                    float rv = mv ? expf(S[tm] - c) : 0.f;
                    v = rv + cs[tm] + ((tm > L) ? 1.f : 0.f);
                } else {
                    int h = i + 1;
                    v = (h <= L && mv) ? -expf(S[(long)h * NN_ + tm] - c) : 0.f;
                }
            }
            if (!(i < 128 && j < 128)) Lrow[j] = v;
            if (q == 0 && j < 128 && i >= 128) Frow[j] = v;
        }
    }
}

// ---------------------------------------------------------------------------
// Pivot-row panels, COLUMN-SPLIT: R_j = Dinv @ A[kb][jt] in place.
// Grid (32, 12). Dual-writes into Fnext slot kb when jt == kb+1.  (= R5)
// ---------------------------------------------------------------------------
__global__ __launch_bounds__(256) void gj_panel(float* __restrict__ Lm,
                                                float* __restrict__ Fnext, int kb)
{
    constexpr int BK = 16;
    __shared__ float Ds[BK][132];
    __shared__ float As2[BK][36];
    int b = blockIdx.x;
    int j = blockIdx.y >> 2;        // 0..2
    int cq = blockIdx.y & 3;        // 0..3
    int jt = j + (j >= kb);
    int c0 = cq * 32;
    int tid = threadIdx.x;
    int tx = tid & 7, ty = tid >> 3;     // ty 0..31 (rows), tx 0..7 (cols)
    float* base = Lm + (long)b * LSTR;
    const float* D = base + (long)(kb * 128) * 512 + kb * 128;   // Dinv, ld 512
    float* Aj = base + (long)(kb * 128) * 512 + jt * 128;        // ld 512
    int drow = tid >> 1, dk8 = (tid & 1) * 8;
    int akr = tid >> 3, acq4 = (tid & 7) * 4;
    bool aload = (akr < BK);
    float acc[4][4] = {};
    float4 dva = *(const float4*)(D + (long)drow * 512 + dk8);
    float4 dvb = *(const float4*)(D + (long)drow * 512 + dk8 + 4);
    float4 av;
    if (aload) av = *(const float4*)(Aj + (long)akr * 512 + c0 + acq4);
    for (int kc = 0; kc < 128; kc += BK) {
        __syncthreads();
        Ds[dk8 + 0][drow] = dva.x; Ds[dk8 + 1][drow] = dva.y;
        Ds[dk8 + 2][drow] = dva.z; Ds[dk8 + 3][drow] = dva.w;
        Ds[dk8 + 4][drow] = dvb.x; Ds[dk8 + 5][drow] = dvb.y;
        Ds[dk8 + 6][drow] = dvb.z; Ds[dk8 + 7][drow] = dvb.w;
        if (aload) *(float4*)&As2[akr][acq4] = av;
        float4 dva2, dvb2, av2;
        if (kc + BK < 128) {
            dva2 = *(const float4*)(D + (long)drow * 512 + kc + BK + dk8);
            dvb2 = *(const float4*)(D + (long)drow * 512 + kc + BK + dk8 + 4);
            if (aload) av2 = *(const float4*)(Aj + (long)(kc + BK + akr) * 512 + c0 + acq4);
        }
        __syncthreads();
        #pragma unroll
        for (int k = 0; k < BK; ++k) {
            float4 a4 = *(const float4*)&Ds[k][ty * 4];
            float4 b4 = *(const float4*)&As2[k][tx * 4];
            float a[4] = {a4.x, a4.y, a4.z, a4.w};
            float bb[4] = {b4.x, b4.y, b4.z, b4.w};
            #pragma unroll
            for (int i = 0; i < 4; ++i)
                #pragma unroll
                for (int jj = 0; jj < 4; ++jj)
                    acc[i][jj] += a[i] * bb[jj];
        }
        dva = dva2; dvb = dvb2; av = av2;
    }
    bool dual = (jt == kb + 1);
    float* Fn = Fnext + (long)b * HSTR + (long)(kb * 128) * 128;
    #pragma unroll
    for (int i = 0; i < 4; ++i) {
        float4 o = make_float4(acc[i][0], acc[i][1], acc[i][2], acc[i][3]);
        *(float4*)(Aj + (long)(ty * 4 + i) * 512 + c0 + tx * 4) = o;
        if (dual) *(float4*)(Fn + (long)(ty * 4 + i) * 128 + c0 + tx * 4) = o;
    }
}

// ---------------------------------------------------------------------------
// LEAN trailing update: 64x128 half-tiles only (grid (32,3,8), 8x4 acc,
// BK=16). UNIFORM — no worker branch, no diag-skip. Low VGPR/LDS.
// A[ib][jt] -= F_ib @ R_jt  (jt==kb: A[ib][kb] = -F_ib @ Dinv).
// Dual-writes column kb+1 halves into Fnext.
// ---------------------------------------------------------------------------
__global__ __launch_bounds__(256) void gj_update64(
    float* __restrict__ Lm, const float* __restrict__ Fbuf,
    float* __restrict__ Fnext, int kb)
{
    constexpr int BK = 16;
    __shared__ float Fs[BK][68];
    __shared__ float Rs[BK][132];
    int b = blockIdx.x;
    int tid = threadIdx.x;
    float* base = Lm + (long)b * LSTR;
    int it = blockIdx.y;            // 0..2
    int ib = it + (it >= kb);
    int sub = blockIdx.z;           // 0..7
    int jt = sub >> 1;
    int half = sub & 1;
    int r0 = half * 64;
    int tx = tid & 31, ty = tid >> 5;    // 32 col-groups x 8 row-groups
    const float* F = Fbuf + (long)b * HSTR + (long)(ib * 128 + r0) * 128;  // ld 128
    const float* R = base + (long)(kb * 128) * 512 + (long)jt * 128;       // ld 512
    float* Cb = base + (long)(ib * 128 + r0) * 512 + jt * 128;
    int frow = tid >> 2, fkq = (tid & 3) << 2;   // F half: 64 rows x 16 k
    int rkr = tid >> 4, rcq = (tid & 15) << 3;   // R tile: 16 k x 128 cols
    float acc[8][4] = {};
    float4 fv  = *(const float4*)(F + (long)frow * 128 + fkq);
    float4 rva = *(const float4*)(R + (long)rkr * 512 + rcq);
    float4 rvb = *(const float4*)(R + (long)rkr * 512 + rcq + 4);
    for (int kc = 0; kc < 128; kc += BK) {
        __syncthreads();
        Fs[fkq + 0][frow] = fv.x; Fs[fkq + 1][frow] = fv.y;
        Fs[fkq + 2][frow] = fv.z; Fs[fkq + 3][frow] = fv.w;
        *(float4*)&Rs[rkr][rcq] = rva;
        *(float4*)&Rs[rkr][rcq + 4] = rvb;
        float4 fv2, rva2, rvb2;
        if (kc + BK < 128) {
            fv2  = *(const float4*)(F + (long)frow * 128 + kc + BK + fkq);
            rva2 = *(const float4*)(R + (long)(kc + BK + rkr) * 512 + rcq);
            rvb2 = *(const float4*)(R + (long)(kc + BK + rkr) * 512 + rcq + 4);
        }
        __syncthreads();
        #pragma unroll
        for (int k = 0; k < BK; ++k) {
            float a[8], bb[4];
            *(float4*)&a[0] = *(const float4*)&Fs[k][ty * 8];
            *(float4*)&a[4] = *(const float4*)&Fs[k][ty * 8 + 4];
            *(float4*)&bb[0] = *(const float4*)&Rs[k][tx * 4];
            #pragma unroll
            for (int i = 0; i < 8; ++i)
                #pragma unroll
                for (int j = 0; j < 4; ++j)
                    acc[i][j] += a[i] * bb[j];
        }
        fv = fv2; rva = rva2; rvb = rvb2;
    }
    bool dual = (jt == kb + 1);
    float* Fn = Fnext + (long)b * HSTR + (long)(ib * 128 + r0) * 128;
    if (jt == kb) {
        #pragma unroll
        for (int i = 0; i < 8; ++i)
            *(float4*)(Cb + (long)(ty * 8 + i) * 512 + tx * 4) =
                make_float4(-acc[i][0], -acc[i][1], -acc[i][2], -acc[i][3]);
    } else {
        #pragma unroll
        for (int i = 0; i < 8; ++i) {
            float4 o = *(const float4*)(Cb + (long)(ty * 8 + i) * 512 + tx * 4);
            o = make_float4(o.x - acc[i][0], o.y - acc[i][1],
                            o.z - acc[i][2], o.w - acc[i][3]);
            *(float4*)(Cb + (long)(ty * 8 + i) * 512 + tx * 4) = o;
            if (dual) *(float4*)(Fn + (long)(ty * 8 + i) * 128 + tx * 4) = o;
        }
    }
}

// ---------------------------------------------------------------------------
// Standalone trailing-diag inversion (512 thr, grid (32)): one batch per
// block, 8 waves on one inversion. Reads raw updated Lm(kb,kb), writes Dinv.
// ---------------------------------------------------------------------------
__global__ __launch_bounds__(512) void inv_k(float* __restrict__ Lm,
                                             float* __restrict__ logdet, int kb)
{
    __shared__ float sm[6][8][132];
    int b = blockIdx.x;
    int tid = threadIdx.x;
    int tx = tid & 15, ty = tid >> 4;   // ty 0..31
    float* Dd = Lm + (long)b * LSTR + (long)(kb * 128) * 512 + kb * 128;
    float r[4][8];
    #pragma unroll
    for (int i = 0; i < 4; ++i) {
        *(float4*)&r[i][0] = *(const float4*)(Dd + (long)(ty * 4 + i) * 512 + tx * 8);
        *(float4*)&r[i][4] = *(const float4*)(Dd + (long)(ty * 4 + i) * 512 + tx * 8 + 4);
    }
    float lacc = invert128_w8(r, tid,
                              (float(*)[8][132])&sm[0],
                              (float(*)[8][132])&sm[2],
                              (float(*)[8][132])&sm[4]);
    #pragma unroll
    for (int i = 0; i < 4; ++i) {
        *(float4*)(Dd + (long)(ty * 4 + i) * 512 + tx * 8) =
            make_float4(r[i][0], r[i][1], r[i][2], r[i][3]);
        *(float4*)(Dd + (long)(ty * 4 + i) * 512 + tx * 8 + 4) =
            make_float4(r[i][4], r[i][5], r[i][6], r[i][7]);
    }
    if (tid == 0) atomicAdd(&logdet[b], lacc);
}

// --------------------------- marginals Y + entropy partials -----------------
__global__ __launch_bounds__(256) void y_k(const float* __restrict__ sc,
                                           const float* __restrict__ Binv,
                                           const int* __restrict__ len,
                                           const unsigned* __restrict__ cu,
                                           float* __restrict__ Y,
                                           float* __restrict__ Ssum)
{
    int b = blockIdx.x;
    int ht = blockIdx.y >> 3, mt = blockIdx.y & 7;
    int h0 = ht * 64, m0 = mt * 64;
    int tid = threadIdx.x;
    int L = len[b];
    float c = mono2f(cu[b]);
    const float* S = sc + (long)b * SSTR;
    const float* Bi = Binv + (long)b * LSTR;
    float* Yb = Y + (long)b * SSTR;
    __shared__ float Bs[64][65];
    __shared__ float Ds[64], C0s[64];
    {
        int hh = tid & 63, m4 = tid >> 6;
        int col = h0 + hh - 1;
        for (int mm = m4; mm < 64; mm += 4) {
            int row = m0 + mm - 1;
            Bs[mm][hh] = (row >= 0 && col >= 0) ? Bi[(long)row * 512 + col] : 0.f;
        }
    }
    if (tid < 64) {
        int row = m0 + tid - 1;
        Ds[tid] = (row >= 0) ? Bi[(long)row * 512 + row] : 0.f;
    } else if (tid < 128) {
        int mm = tid - 64, row = m0 + mm - 1;
        C0s[mm] = (row >= 0) ? Bi[(long)row * 512] : 0.f;
    }
    __syncthreads();
    int mm = tid & 63, hq = tid >> 6;
    int m = m0 + mm;
    float lsum = 0.f;
    bool mvalid = (m >= 1 && m <= L);
    float dterm = (m >= 2) ? Ds[mm] : 0.f;
    #pragma unroll
    for (int hi = 0; hi < 16; ++hi) {
        int hh = hq * 16 + hi;
        int h = h0 + hh;
        float s = S[(long)h * NN_ + m];
        float y = 0.f;
        if (mvalid && h <= L && h != m) {
            float a = expf(s - c);
            float g;
            if (h == 0) g = C0s[mm] + dterm;
            else g = dterm - ((h >= 2) ? Bs[mm][hh] : 0.f);
            y = a * g;
        }
        Yb[(long)h * NN_ + m] = y;
        lsum += y * s;
    }
    __shared__ float red[256];
    red[tid] = lsum; __syncthreads();
    for (int off = 128; off; off >>= 1) {
        if (tid < off) red[tid] += red[tid + off];
        __syncthreads();
    }
    if (tid == 0) atomicAdd(&Ssum[b], red[0]);
}

// finalize + re-zero accumulators for the next iteration
__global__ void fin_k(const int* __restrict__ len, unsigned* __restrict__ cu,
                      float* __restrict__ logdet, float* __restrict__ Ssum,
                      float* __restrict__ outLogZ, float* __restrict__ outEntr)
{
    int b = threadIdx.x;
    if (b < 32) {
        float c = mono2f(cu[b]);
        float lz = logdet[b] + (float)len[b] * c;
        outLogZ[b] = lz;
        outEntr[b] = lz - Ssum[b];
        cu[b] = 0u;
        logdet[b] = 0.f;
        Ssum[b] = 0.f;
    }
}

// ---------------------------------------------------------------------------
extern "C" void kernel_launch(void* const* d_in, const int* in_sizes, int n_in,
                              void* d_out, int out_size, void* d_ws, size_t ws_size,
                              hipStream_t stream)
{
    const float* Xh = (const float*)d_in[0];
    const float* Xm = (const float*)d_in[1];
    const int*   len = (const int*)d_in[2];
    const float* Wh = (const float*)d_in[3];
    const float* bh = (const float*)d_in[4];
    const float* Wm = (const float*)d_in[5];
    const float* bm = (const float*)d_in[6];
    const float* V  = (const float*)d_in[7];

    float* ws = (float*)d_ws;
    constexpr long U = 2097152;           // 32*512*128
    float* H0 = ws;
    float* M0 = ws + U;
    float* Ha = ws + 2 * U;
    float* Ma = ws + 3 * U;
    float* Hb = ws + 4 * U;
    float* Mb = ws + 5 * U;
    float* T1 = ws + 6 * U;               // P = H@V (live across GJ!)
    float* Yt = ws + 7 * U;               // Q scratch (feedback) / Fbuf ping (GJ)
    float* Lm = ws + 8 * U;               // 32 x 512 x 512
    float* cs = ws + 12 * U;              // colsum 32*512
    float* scal = ws + 12 * U + 16384;    // c_u[32] | logdet[32] | Ssum[32]
    unsigned* cu = (unsigned*)scal;
    float* logdet = scal + 32;
    float* Ssum = scal + 64;

    float* Sout = (float*)d_out;                        // scores  [32,512,512]
    float* outLogZ = (float*)d_out + 8388608;           // logZ    [32]
    float* Yout = (float*)d_out + 8388640;              // Y       [32,512,512]
    float* outEntr = (float*)d_out + 8388640 + 8388608; // entr    [32]

    zero_scal<<<1, 96, 0, stream>>>(scal);

    // H0 = Xh@Wh^T + bh ; H = relu(H0)   (and same for M)
    gemm64<0,1,1><<<dim3(256, 2, 1), 256, 0, stream>>>(
        Xh, Wh, Ha, bh, H0, 16384, DH, DIN, 0, 0, 0, 0);
    gemm64<0,1,1><<<dim3(256, 2, 1), 256, 0, stream>>>(
        Xm, Wm, Ma, bm, M0, 16384, DH, DIN, 0, 0, 0, 0);

    float* Hc = Ha; float* Mc = Ma; float* Hn = Hb; float* Mn = Mb;
    for (int t = 0; t < NITER; ++t) {
        if (t > 0) {
            // Q = Mc @ V^T (Yt); Hn = relu(H0 + Y@Q); Mn = relu(M0 + Y^T@P)
            gemm64<0,1,0><<<dim3(8,2,BB),256,0,stream>>>(
                Mc, V, Yt, nullptr, nullptr, 512, DH, DH, HSTR, 0, HSTR, 0);
            gemm32<0><<<dim3(16,2,BB),256,0,stream>>>(
                Yout, Yt, Hn, H0, 512, DH, 512, SSTR, HSTR, HSTR, HSTR);
            gemm32<1><<<dim3(16,2,BB),256,0,stream>>>(
                Yout, T1, Mn, M0, 512, DH, 512, SSTR, HSTR, HSTR, HSTR);
            { float* tmp = Hc; Hc = Hn; Hn = tmp; }
            { float* tmp = Mc; Mc = Mn; Mn = tmp; }
        }
        // P = Hc @ V (T1, persists to next feedback); scores = P @ Mc^T
        gemm64<0,0,0><<<dim3(8,2,BB),256,0,stream>>>(
            Hc, V, T1, nullptr, nullptr, 512, DH, DH, HSTR, 0, HSTR, 0);
        score_gemm<<<dim3(4,4,BB),256,0,stream>>>(T1, Mc, Sout, len, cu);

        // colsum -> diag-0 build+invert (8-wave) -> lean streaming build
        colsum_k<<<dim3(BB,8),256,0,stream>>>(Sout, len, cu, cs);
        build_diag0<<<dim3(BB),512,0,stream>>>(Sout, len, cu, cs, Lm, logdet);
        build_rows<<<dim3(BB,64),256,0,stream>>>(Sout, len, cu, cs, Lm, Yt);

        // Fbuf ping-pong: even kb reads Yt, writes Hn (dead during GJ); odd flips
        float* Fbufs[2] = {Yt, Hn};
        for (int kb = 0; kb < 4; ++kb) {
            float* Fcur  = Fbufs[kb & 1];
            float* Fnext = Fbufs[(kb + 1) & 1];
            gj_panel<<<dim3(BB,12),256,0,stream>>>(Lm, Fnext, kb);
            gj_update64<<<dim3(BB,3,8),256,0,stream>>>(Lm, Fcur, Fnext, kb);
            if (kb < 3)
                inv_k<<<dim3(BB),512,0,stream>>>(Lm, logdet, kb + 1);
        }
        y_k<<<dim3(BB,64),256,0,stream>>>(Sout, Lm, len, cu, Yout, Ssum);
        fin_k<<<1,32,0,stream>>>(len, cu, logdet, Ssum, outLogZ, outEntr);
    }
}